// Round 7
// baseline (29252.841 us; speedup 1.0000x reference)
//
#include <hip/hip_runtime.h>

#define BB 32
#define SS 64
#define TT 64
#define VV 32000
#define EE 512
#define HH 1024
#define GRID 512
#define BLK 512
#define NCAND 250
#define ASTR 16          // barrier slot stride in ints (64B)
#define FLTMAX 3.402823466e38f

typedef unsigned long long u64;

struct Par {
  const int *src, *tgt, *tmask;
  const float *enc_embed, *dec_embed;
  const float *enc_wih0, *enc_whh0, *enc_b0;
  const float *enc_wih1, *enc_whh1, *enc_b1;
  const float *dec_wih0, *dec_whh0, *dec_b0;
  const float *dec_wih1, *dec_whh1, *dec_b1;
  const float *fc_w, *fc_b;
  float *out;
  float *hA0, *hA1, *hB0, *hB1;   // cross-block state (coherent access only)
  float *cA, *cB;                 // block-private cell state [256][128] each
  float2 *cand;                   // [250][32]
  int *arr; int *gen;
};

__device__ __forceinline__ float sigf(float x) { return 1.0f / (1.0f + expf(-x)); }

// ---- coherent agent-scope RELAXED access (no L2-invalidate fences) --------
__device__ __forceinline__ float2 ldc2(const float* p) {
  u64 v = __hip_atomic_load((const u64*)p, __ATOMIC_RELAXED, __HIP_MEMORY_SCOPE_AGENT);
  union { u64 u; float2 f; } c; c.u = v; return c.f;
}
__device__ __forceinline__ void stc2(float* p, float x, float y) {
  union { u64 u; float2 f; } c; c.f = make_float2(x, y);
  __hip_atomic_store((u64*)p, c.u, __ATOMIC_RELAXED, __HIP_MEMORY_SCOPE_AGENT);
}
__device__ __forceinline__ void stc1(float* p, float x) {
  __hip_atomic_store(p, x, __ATOMIC_RELAXED, __HIP_MEMORY_SCOPE_AGENT);
}

// ---------------------------------------------------------------------------
// Fence-free grid barrier v4: one 64B line per arrival slot (no cross-block
// line sharing on stores); gen replicated 8x so only ~64 waiters poll a line.
// ---------------------------------------------------------------------------
__device__ __forceinline__ void gbar(int* arr, int* gen, int target) {
  __syncthreads();
  asm volatile("s_waitcnt vmcnt(0)" ::: "memory");
  if (blockIdx.x == 0) {
    if (threadIdx.x < 64) {
      const int s = threadIdx.x;
      for (;;) {
        bool ok = true;
#pragma unroll
        for (int o = 0; o < GRID; o += 64) {
          int idx = s + o;
          int a = (idx == 0) ? target
              : __hip_atomic_load(arr + idx * ASTR, __ATOMIC_RELAXED, __HIP_MEMORY_SCOPE_AGENT);
          ok &= (a >= target);
        }
        if (__all(ok)) break;
        __builtin_amdgcn_s_sleep(2);
      }
    }
    __syncthreads();
    if (threadIdx.x < 8)
      __hip_atomic_store(gen + threadIdx.x * ASTR, target, __ATOMIC_RELAXED, __HIP_MEMORY_SCOPE_AGENT);
  } else {
    if (threadIdx.x == 0) {
      __hip_atomic_store(arr + blockIdx.x * ASTR, target, __ATOMIC_RELAXED, __HIP_MEMORY_SCOPE_AGENT);
      while (__hip_atomic_load(gen + (blockIdx.x & 7) * ASTR, __ATOMIC_RELAXED, __HIP_MEMORY_SCOPE_AGENT) < target)
        __builtin_amdgcn_s_sleep(2);
    }
    __syncthreads();
  }
  asm volatile("" ::: "memory");
}

// ---------------------------------------------------------------------------
// LSTM partial accumulate (u-tile 4 -> 16 gate rows, acc[16]).
// Register-prefetched, ping-pong LDS wbuf, ONE __syncthreads per 256-chunk.
// ---------------------------------------------------------------------------
__device__ __forceinline__ void lstm_accum4(
    const float* __restrict__ tab, const int* __restrict__ stokL,
    const float* __restrict__ xcoh, int lenx,
    const float* __restrict__ W, int u0,
    float* __restrict__ acc, float* __restrict__ SH)
{
  const int tid = threadIdx.x;
  const int b = tid & 31, tc = tid >> 5;
  const int lane = tid & 63, wid = tid >> 6;
  const int r2 = wid + 8;
  const float* wr1 = W + (size_t)((wid >> 2) * HH + u0 + (wid & 3)) * lenx + (lane << 2);
  const float* wr2 = W + (size_t)((r2 >> 2) * HH + u0 + (r2 & 3)) * lenx + (lane << 2);
  const int nc = lenx >> 8;
  float4 wA = *reinterpret_cast<const float4*>(wr1);
  float4 wB = *reinterpret_cast<const float4*>(wr2);
  for (int c = 0; c < nc; ++c) {
    float* wb = SH + ((c & 1) << 12);
    *reinterpret_cast<float4*>(wb + (wid << 8) + (lane << 2)) = wA;
    *reinterpret_cast<float4*>(wb + (r2 << 8) + (lane << 2)) = wB;
    if (c + 1 < nc) {
      wA = *reinterpret_cast<const float4*>(wr1 + ((c + 1) << 8));
      wB = *reinterpret_cast<const float4*>(wr2 + ((c + 1) << 8));
    }
    float xr[16];
    const int col = (c << 8) + (tc << 4);
    if (tab) {
      const int tk = stokL[b];
      if (tk) {
        const float4* s4 = reinterpret_cast<const float4*>(tab + (size_t)tk * lenx + col);
#pragma unroll
        for (int e = 0; e < 4; ++e) {
          float4 v = s4[e];
          xr[4*e] = v.x; xr[4*e+1] = v.y; xr[4*e+2] = v.z; xr[4*e+3] = v.w;
        }
      } else {
#pragma unroll
        for (int e = 0; e < 16; ++e) xr[e] = 0.f;
      }
    } else {
      const float* xp = xcoh + (size_t)b * lenx + col;
#pragma unroll
      for (int e = 0; e < 8; ++e) {
        float2 v = ldc2(xp + 2 * e); xr[2*e] = v.x; xr[2*e+1] = v.y;
      }
    }
    __syncthreads();
#pragma unroll
    for (int q = 0; q < 16; ++q) {
      const float4* w4 = reinterpret_cast<const float4*>(wb + (q << 8) + (tc << 4));
      float4 w0 = w4[0], w1 = w4[1], w2 = w4[2], w3 = w4[3];
      acc[q] += xr[0]*w0.x + xr[1]*w0.y + xr[2]*w0.z + xr[3]*w0.w
              + xr[4]*w1.x + xr[5]*w1.y + xr[6]*w1.z + xr[7]*w1.w
              + xr[8]*w2.x + xr[9]*w2.y + xr[10]*w2.z + xr[11]*w2.w
              + xr[12]*w3.x + xr[13]*w3.y + xr[14]*w3.z + xr[15]*w3.w;
    }
  }
}

// cross-slice reduce + cell + coherent h-store (red at SH+8192)
__device__ __forceinline__ void lstm_finish4(
    const float* __restrict__ bias, int u0,
    const float* __restrict__ acc, float* __restrict__ cpriv,
    float* __restrict__ hdst, float* __restrict__ SH)
{
  const int tid = threadIdx.x;
  const int b = tid & 31, tc = tid >> 5;
  float* red = SH + 8192;
  __syncthreads();
#pragma unroll
  for (int q = 0; q < 16; ++q) red[(tc * 16 + q) * 33 + b] = acc[q];
  __syncthreads();
  if (tid < 128) {
    int bb = tid & 31, ul = tid >> 5;
    float g[4];
#pragma unroll
    for (int gg = 0; gg < 4; ++gg) {
      float s = bias[gg * HH + u0 + ul];
#pragma unroll
      for (int t2 = 0; t2 < 16; ++t2) s += red[(t2 * 16 + gg * 4 + ul) * 33 + bb];
      g[gg] = s;
    }
    float cn = sigf(g[1]) * cpriv[(bb << 2) + ul] + sigf(g[0]) * tanhf(g[2]);
    float hn = sigf(g[3]) * tanhf(cn);
    cpriv[(bb << 2) + ul] = cn;
    stc1(hdst + (size_t)bb * HH + u0 + ul, hn);
  }
  __syncthreads();
}

// ---------------------------------------------------------------------------
// FC tile: 128 j per tile, 2 j per lane, wave wv -> 4 b's, acc[8].
// w loads lane-distinct (line-efficient); h broadcast from LDS (wave-uniform).
// ---------------------------------------------------------------------------
__device__ __forceinline__ void fc_tile(const Par& p, const float* __restrict__ hsrc,
                                        int t, int fcid, float* __restrict__ SH)
{
  const int tid = threadIdx.x;
  const int jl = tid & 63;
  const int wv = tid >> 6;
  const int jbase = fcid << 7;
  const int j0 = jbase + (jl << 1);
  const float* w0 = p.fc_w + (size_t)j0 * HH;
  const float* w1 = w0 + HH;
  float acc[8] = {0.f,0.f,0.f,0.f,0.f,0.f,0.f,0.f};

  for (int r = 0; r < 4; ++r) {
    __syncthreads();
    {   // stage h chunk [32][256] -> SH[32][264]
      int sb = tid >> 4, c0 = (tid & 15) << 4;
      const float* xp = hsrc + (size_t)sb * HH + (r << 8) + c0;
      float* dd = SH + sb * 264 + c0;
#pragma unroll
      for (int e = 0; e < 8; ++e) {
        float2 v = ldc2(xp + 2 * e); dd[2*e] = v.x; dd[2*e+1] = v.y;
      }
    }
    __syncthreads();
    const float* pw0 = w0 + (r << 8);
    const float* pw1 = w1 + (r << 8);
    const float* px  = SH + (wv << 2) * 264;
#pragma unroll 4
    for (int kk = 0; kk < 256; kk += 4) {
      float4 a0 = *reinterpret_cast<const float4*>(pw0 + kk);
      float4 a1 = *reinterpret_cast<const float4*>(pw1 + kk);
#pragma unroll
      for (int bb = 0; bb < 4; ++bb) {
        float4 x4 = *reinterpret_cast<const float4*>(px + bb * 264 + kk);
        acc[bb]     += a0.x*x4.x + a0.y*x4.y + a0.z*x4.z + a0.w*x4.w;
        acc[4 + bb] += a1.x*x4.x + a1.y*x4.y + a1.z*x4.z + a1.w*x4.w;
      }
    }
  }
  float b0 = p.fc_b[j0], b1 = p.fc_b[j0 + 1];
  float* SA = SH + 8704;            // [32][130]
  __syncthreads();
#pragma unroll
  for (int bb = 0; bb < 4; ++bb) {
    int b = (wv << 2) + bb;
    float v0 = acc[bb] + b0, v1 = acc[4 + bb] + b1;
    union { double d; float2 f; } uu; uu.f = make_float2(v0, v1);
    __builtin_nontemporal_store(uu.d, reinterpret_cast<double*>(
        p.out + (size_t)b * TT * VV + (size_t)t * VV + j0));
    SA[b * 130 + (jl << 1)] = v0; SA[b * 130 + (jl << 1) + 1] = v1;
  }
  __syncthreads();
  if (tid < 32) {                   // first-max over this tile's 128 j
    float bv = -FLTMAX; int bi = 0;
    for (int jj = 0; jj < 128; ++jj) {
      float v = SA[tid * 130 + jj];
      if (v > bv) { bv = v; bi = jbase + jj; }
    }
    stc2((float*)&p.cand[fcid * 32 + tid], bv, __int_as_float(bi));
  }
  __syncthreads();
}

// ---------------------------------------------------------------------------
__global__ __launch_bounds__(BLK, 4) void mega(Par p) {
  __shared__ __attribute__((aligned(16))) float SH[16640]; // wbuf dbuf + red / FC stage+SA
  __shared__ float sav[16][32];
  __shared__ int   sai[16][32];
  __shared__ int   stok[32];

  const int tid = threadIdx.x;
  const int bid = blockIdx.x;
  const int gid = bid * BLK + tid;
  const bool ev = !(bid & 1);
  const int id = bid >> 1;              // 0..255 within parity class
  const int u0 = id * 4;
  int gen = 0;

  // ---- init
  for (int i = gid * 2; i < 4 * BB * HH; i += GRID * BLK * 2)
    stc2(p.hA0 + i, 0.f, 0.f);                 // hA0..hB1 contiguous
  if (tid < 128) {
    if (ev) p.cA[id * 128 + tid] = 0.f; else p.cB[id * 128 + tid] = 0.f;
  }
  for (long g2 = gid; g2 < (long)BB * VV; g2 += (long)GRID * BLK) {
    int b = (int)(g2 / VV), v = (int)(g2 - (long)b * VV);
    __builtin_nontemporal_store(0.f, p.out + (size_t)b * TT * VV + v);
  }
  gbar(p.arr, p.gen, ++gen);

  // ---- encoder: evens L0(tt), odds L1(tt-1)
  for (int tt = 0; tt <= SS; ++tt) {
    const int par = tt & 1;
    float* hA_w = par ? p.hA1 : p.hA0;
    float* hA_r = par ? p.hA0 : p.hA1;
    float* hB_w = par ? p.hB0 : p.hB1;
    float* hB_r = par ? p.hB1 : p.hB0;
    if (ev) {
      if (tt < SS) {
        if (tid < 32) stok[tid] = p.src[tid * SS + tt];
        __syncthreads();
        float acc[16] = {0.f};
        lstm_accum4(p.enc_embed, stok, nullptr, EE, p.enc_wih0, u0, acc, SH);
        lstm_accum4(nullptr, nullptr, hA_r, HH, p.enc_whh0, u0, acc, SH);
        lstm_finish4(p.enc_b0, u0, acc, p.cA + id * 128, hA_w, SH);
      }
    } else {
      if (tt >= 1) {
        float acc[16] = {0.f};
        lstm_accum4(nullptr, nullptr, hA_r, HH, p.enc_wih1, u0, acc, SH);
        lstm_accum4(nullptr, nullptr, hB_r, HH, p.enc_whh1, u0, acc, SH);
        lstm_finish4(p.enc_b1, u0, acc, p.cB + id * 128, hB_w, SH);
      }
    }
    gbar(p.arr, p.gen, ++gen);
  }

  // ---- decoder
  for (int k = 0; k < TT - 1; ++k) {
    const int par = k & 1;
    float* hA_r = par ? p.hA0 : p.hA1;
    float* hA_w = par ? p.hA1 : p.hA0;
    float* hB_r = par ? p.hB0 : p.hB1;
    float* hB_w = par ? p.hB1 : p.hB0;
    const bool teach = (k == 0) || (p.tmask[k] > 0);

    if (teach) {
      // A: evens full L0 (token known) || odds FC(k-1)
      if (ev) {
        if (tid < 32) stok[tid] = p.tgt[tid * TT + k];
        __syncthreads();
        float acc[16] = {0.f};
        lstm_accum4(p.dec_embed, stok, nullptr, EE, p.dec_wih0, u0, acc, SH);
        lstm_accum4(nullptr, nullptr, hA_r, HH, p.dec_whh0, u0, acc, SH);
        lstm_finish4(p.dec_b0, u0, acc, p.cA + id * 128, hA_w, SH);
      } else if (k > 0 && id < NCAND) {
        fc_tile(p, hB_r, k, id, SH);
      }
      gbar(p.arr, p.gen, ++gen);
      // B: odds full L1
      if (!ev) {
        float acc[16] = {0.f};
        lstm_accum4(nullptr, nullptr, hB_r, HH, p.dec_whh1, u0, acc, SH);
        lstm_accum4(nullptr, nullptr, hA_w, HH, p.dec_wih1, u0, acc, SH);
        lstm_finish4(p.dec_b1, u0, acc, p.cB + id * 128, hB_w, SH);
      }
      gbar(p.arr, p.gen, ++gen);
    } else {
      float accL[16];
#pragma unroll
      for (int q = 0; q < 16; ++q) accL[q] = 0.f;
      // A': evens L0 h-part (acc in regs) || odds FC(k-1)
      if (ev) {
        lstm_accum4(nullptr, nullptr, hA_r, HH, p.dec_whh0, u0, accL, SH);
      } else if (id < NCAND) {
        fc_tile(p, hB_r, k, id, SH);
      }
      gbar(p.arr, p.gen, ++gen);
      // B': evens amred->token, L0 x-part + cell || odds L1 h-part (regs)
      if (ev) {
        {
          int grp = tid >> 5, b2 = tid & 31;
          float bv = -FLTMAX; int bi = 0x7fffffff;
          for (int s = grp; s < NCAND; s += 16) {
            float2 cv = ldc2((const float*)&p.cand[s * 32 + b2]);
            int ci = __float_as_int(cv.y);
            if (cv.x > bv || (cv.x == bv && ci < bi)) { bv = cv.x; bi = ci; }
          }
          sav[grp][b2] = bv; sai[grp][b2] = bi;
          __syncthreads();
          if (tid < 32) {
            float v = sav[0][tid]; int vi = sai[0][tid];
#pragma unroll
            for (int s = 1; s < 16; ++s) {
              float w = sav[s][tid]; int wi = sai[s][tid];
              if (w > v || (w == v && wi < vi)) { v = w; vi = wi; }
            }
            stok[tid] = vi;
          }
          __syncthreads();
        }
        lstm_accum4(p.dec_embed, stok, nullptr, EE, p.dec_wih0, u0, accL, SH);
        lstm_finish4(p.dec_b0, u0, accL, p.cA + id * 128, hA_w, SH);
      } else {
        lstm_accum4(nullptr, nullptr, hB_r, HH, p.dec_whh1, u0, accL, SH);
      }
      gbar(p.arr, p.gen, ++gen);
      // C': odds L1 x-part + cell
      if (!ev) {
        lstm_accum4(nullptr, nullptr, hA_w, HH, p.dec_wih1, u0, accL, SH);
        lstm_finish4(p.dec_b1, u0, accL, p.cB + id * 128, hB_w, SH);
      }
      gbar(p.arr, p.gen, ++gen);
    }
  }

  // ---- final FC: logits t=63 from hB written at k=62 (par=0 -> hB0)
  if (!ev || true) { /* uniform path split below */ }
  if ((bid & 1) && id < NCAND) fc_tile(p, p.hB0, TT - 1, id, SH);
}

// ---------------------------------------------------------------------------
extern "C" void kernel_launch(void* const* d_in, const int* in_sizes, int n_in,
                              void* d_out, int out_size, void* d_ws, size_t ws_size,
                              hipStream_t stream) {
  Par p;
  p.src       = (const int*)d_in[0];
  p.tgt       = (const int*)d_in[1];
  p.tmask     = (const int*)d_in[2];
  p.enc_embed = (const float*)d_in[3];
  p.dec_embed = (const float*)d_in[4];
  p.enc_wih0  = (const float*)d_in[5];
  p.enc_whh0  = (const float*)d_in[6];
  p.enc_b0    = (const float*)d_in[7];
  p.enc_wih1  = (const float*)d_in[8];
  p.enc_whh1  = (const float*)d_in[9];
  p.enc_b1    = (const float*)d_in[10];
  p.dec_wih0  = (const float*)d_in[11];
  p.dec_whh0  = (const float*)d_in[12];
  p.dec_b0    = (const float*)d_in[13];
  p.dec_wih1  = (const float*)d_in[14];
  p.dec_whh1  = (const float*)d_in[15];
  p.dec_b1    = (const float*)d_in[16];
  p.fc_w      = (const float*)d_in[17];
  p.fc_b      = (const float*)d_in[18];
  p.out       = (float*)d_out;

  p.arr = (int*)d_ws;                         // 512 slots x 64B
  p.gen = (int*)d_ws + 512 * ASTR;            // 8 slots x 64B
  float* f = (float*)((char*)d_ws + 36864);
  p.hA0 = f; f += BB * HH;
  p.hA1 = f; f += BB * HH;
  p.hB0 = f; f += BB * HH;
  p.hB1 = f; f += BB * HH;
  p.cA  = f; f += 256 * 128;
  p.cB  = f; f += 256 * 128;
  p.cand = (float2*)f; f += NCAND * 32 * 2;

  hipMemsetAsync(d_ws, 0, 36864, stream);
  mega<<<dim3(GRID), dim3(BLK), 0, stream>>>(p);
}

// Round 9
// 16546.429 us; speedup vs baseline: 1.7679x; 1.7679x over previous
//
#include <hip/hip_runtime.h>

#define BB 32
#define SS 64
#define TT 64
#define VV 32000
#define EE 512
#define HH 1024
#define GRID 512
#define BLK 512
#define NFC 500          // FC tiles of 64 j
#define ASTR 16          // barrier slot stride in ints (64B)
#define FLTMAX 3.402823466e38f

typedef unsigned long long u64;

struct Par {
  const int *src, *tgt, *tmask;
  const float *enc_embed, *dec_embed;
  const float *enc_wih0, *enc_whh0, *enc_b0;
  const float *enc_wih1, *enc_whh1, *enc_b1;
  const float *dec_wih0, *dec_whh0, *dec_b0;
  const float *dec_wih1, *dec_whh1, *dec_b1;
  const float *fc_w, *fc_b;
  float *out;
  float *hA0, *hA1;               // layer-0 h double buffer (coherent)
  float *hBall;                   // 64 slots x [32][1024] h-history (coherent)
  float *cA, *cB;                 // block-private cell state
  float2 *cand;                   // [500][32]
  int *tok;                       // [32]
  int *arr; int *gen;
};

__device__ __forceinline__ float sigf(float x) { return 1.0f / (1.0f + expf(-x)); }

// ---- coherent agent-scope RELAXED access (no L2-invalidate fences) --------
__device__ __forceinline__ float2 ldc2(const float* p) {
  u64 v = __hip_atomic_load((const u64*)p, __ATOMIC_RELAXED, __HIP_MEMORY_SCOPE_AGENT);
  union { u64 u; float2 f; } c; c.u = v; return c.f;
}
__device__ __forceinline__ void stc2(float* p, float x, float y) {
  union { u64 u; float2 f; } c; c.f = make_float2(x, y);
  __hip_atomic_store((u64*)p, c.u, __ATOMIC_RELAXED, __HIP_MEMORY_SCOPE_AGENT);
}
__device__ __forceinline__ void stc1(float* p, float x) {
  __hip_atomic_store(p, x, __ATOMIC_RELAXED, __HIP_MEMORY_SCOPE_AGENT);
}
__device__ __forceinline__ int ldci(const int* p) {
  return __hip_atomic_load(p, __ATOMIC_RELAXED, __HIP_MEMORY_SCOPE_AGENT);
}

// ---------------------------------------------------------------------------
// Fence-free grid barrier: 64B-stride arrival slots, 8 replicated gen lines.
// REQUIRES all 512 blocks co-resident (2 blocks/CU -> launch_bounds(512,4)).
// ---------------------------------------------------------------------------
__device__ __forceinline__ void gbar(int* arr, int* gen, int target) {
  __syncthreads();
  asm volatile("s_waitcnt vmcnt(0)" ::: "memory");
  if (blockIdx.x == 0) {
    if (threadIdx.x < 64) {
      const int s = threadIdx.x;
      for (;;) {
        bool ok = true;
#pragma unroll
        for (int o = 0; o < GRID; o += 64) {
          int idx = s + o;
          int a = (idx == 0) ? target
              : __hip_atomic_load(arr + idx * ASTR, __ATOMIC_RELAXED, __HIP_MEMORY_SCOPE_AGENT);
          ok &= (a >= target);
        }
        if (__all(ok)) break;
        __builtin_amdgcn_s_sleep(2);
      }
    }
    __syncthreads();
    if (threadIdx.x < 8)
      __hip_atomic_store(gen + threadIdx.x * ASTR, target, __ATOMIC_RELAXED, __HIP_MEMORY_SCOPE_AGENT);
  } else {
    if (threadIdx.x == 0) {
      __hip_atomic_store(arr + blockIdx.x * ASTR, target, __ATOMIC_RELAXED, __HIP_MEMORY_SCOPE_AGENT);
      while (__hip_atomic_load(gen + (blockIdx.x & 7) * ASTR, __ATOMIC_RELAXED, __HIP_MEMORY_SCOPE_AGENT) < target)
        __builtin_amdgcn_s_sleep(2);
    }
    __syncthreads();
  }
  asm volatile("" ::: "memory");
}

// ---------------------------------------------------------------------------
// LSTM partial accumulate (u-tile 4 -> 16 gate rows, acc[16]); weights staged
// via LDS (coalesced 1KB/instr), read back as 2-way-broadcast b128 (free).
// Threads: b = tid&31, tc = tid>>5 (16 k-slices of 16 per 256-chunk).
// ---------------------------------------------------------------------------
__device__ __forceinline__ void lstm_accum(
    const float* __restrict__ tab, const int* __restrict__ stokL,
    const float* __restrict__ xcoh, int lenx,
    const float* __restrict__ W, int u0,
    float* __restrict__ acc, float* __restrict__ wbuf)
{
  const int tid = threadIdx.x;
  const int b = tid & 31, tc = tid >> 5;
  const int lane = tid & 63, wid = tid >> 6;
  const int r2 = wid + 8;
  const float* wr1 = W + (size_t)((wid >> 2) * HH + u0 + (wid & 3)) * lenx + (lane << 2);
  const float* wr2 = W + (size_t)((r2  >> 2) * HH + u0 + (r2  & 3)) * lenx + (lane << 2);
  const int ncx = lenx >> 8;
  for (int c = 0; c < ncx; ++c) {
    const int col = c << 8;
    __syncthreads();
    {
      float4 wA = *reinterpret_cast<const float4*>(wr1 + col);
      float4 wB = *reinterpret_cast<const float4*>(wr2 + col);
      *reinterpret_cast<float4*>(wbuf + (wid << 8) + (lane << 2)) = wA;
      *reinterpret_cast<float4*>(wbuf + (r2  << 8) + (lane << 2)) = wB;
    }
    float xr[16];
    if (tab) {
      const int tk = stokL[b];
      if (tk) {
        const float4* s4 = reinterpret_cast<const float4*>(
            tab + (size_t)tk * lenx + col + (tc << 4));
#pragma unroll
        for (int e = 0; e < 4; ++e) {
          float4 v = s4[e];
          xr[e*4] = v.x; xr[e*4+1] = v.y; xr[e*4+2] = v.z; xr[e*4+3] = v.w;
        }
      } else {
#pragma unroll
        for (int e = 0; e < 16; ++e) xr[e] = 0.f;
      }
    } else {
      const float* xp = xcoh + (size_t)b * lenx + col + (tc << 4);
#pragma unroll
      for (int e = 0; e < 8; ++e) {
        float2 v = ldc2(xp + 2*e); xr[2*e] = v.x; xr[2*e+1] = v.y;
      }
    }
    __syncthreads();
#pragma unroll
    for (int q = 0; q < 16; ++q) {
      const float4* w4 = reinterpret_cast<const float4*>(wbuf + (q << 8) + (tc << 4));
      float4 w0 = w4[0], w1 = w4[1], w2 = w4[2], w3 = w4[3];
      acc[q] += xr[0]*w0.x + xr[1]*w0.y + xr[2]*w0.z + xr[3]*w0.w
              + xr[4]*w1.x + xr[5]*w1.y + xr[6]*w1.z + xr[7]*w1.w
              + xr[8]*w2.x + xr[9]*w2.y + xr[10]*w2.z + xr[11]*w2.w
              + xr[12]*w3.x + xr[13]*w3.y + xr[14]*w3.z + xr[15]*w3.w;
    }
  }
}

// cross-slice reduce + cell + coherent h-store (red at SH+4096)
__device__ __forceinline__ void lstm_finish(
    const float* __restrict__ bias, int u0,
    const float* __restrict__ acc, float* __restrict__ cpriv,
    float* __restrict__ hdst, float* __restrict__ SH)
{
  const int tid = threadIdx.x;
  const int b = tid & 31, tc = tid >> 5;
  float* red = SH + 4096;
  __syncthreads();
#pragma unroll
  for (int q = 0; q < 16; ++q) red[(tc * 16 + q) * 33 + b] = acc[q];
  __syncthreads();
  if (tid < 128) {
    int bb = tid & 31, ul = tid >> 5;
    float g[4];
#pragma unroll
    for (int gg = 0; gg < 4; ++gg) {
      float s = bias[gg * HH + u0 + ul];
#pragma unroll
      for (int t2 = 0; t2 < 16; ++t2) s += red[(t2 * 16 + gg * 4 + ul) * 33 + bb];
      g[gg] = s;
    }
    float cn = sigf(g[1]) * cpriv[(bb << 2) + ul] + sigf(g[0]) * tanhf(g[2]);
    float hn = sigf(g[3]) * tanhf(cn);
    cpriv[(bb << 2) + ul] = cn;
    stc1(hdst + (size_t)bb * HH + u0 + ul, hn);
  }
  __syncthreads();
}

// ---------------------------------------------------------------------------
// FC tile: 64 j per tile. thread: jl=tid&31 -> j-pair, bg=(tid>>5)&7 -> 4 b's,
// kh=tid>>8 -> k-half of each 256-chunk. acc[8] only.
// ---------------------------------------------------------------------------
__device__ __forceinline__ void fc_tile(const Par& p, const float* __restrict__ hsrc,
                                        int t, int fcid, float* __restrict__ SH)
{
  const int tid = threadIdx.x;
  const int jl = tid & 31;
  const int bg = (tid >> 5) & 7;
  const int kh = tid >> 8;
  const int jbase = fcid * 64;
  const float* w0 = p.fc_w + (size_t)(jbase + 2 * jl) * HH;
  const float* w1 = w0 + HH;
  float acc[8] = {0.f,0.f,0.f,0.f,0.f,0.f,0.f,0.f};

  for (int r = 0; r < 4; ++r) {
    __syncthreads();
    {   // stage h chunk [32][256] -> SH[32][264]
      int sb = tid >> 4, c0 = (tid & 15) << 4;
      const float* xp = hsrc + (size_t)sb * HH + (r << 8) + c0;
      float* dd = SH + sb * 264 + c0;
#pragma unroll
      for (int e = 0; e < 8; ++e) {
        float2 v = ldc2(xp + 2 * e); dd[2*e] = v.x; dd[2*e+1] = v.y;
      }
    }
    __syncthreads();
    const int kb = (r << 8) + (kh << 7);
    const float* pw0 = w0 + kb;
    const float* pw1 = w1 + kb;
    const float* px  = SH + (bg << 2) * 264 + (kh << 7);
#pragma unroll 4
    for (int kk = 0; kk < 128; kk += 8) {
      float4 a0  = *reinterpret_cast<const float4*>(pw0 + kk);
      float4 a0b = *reinterpret_cast<const float4*>(pw0 + kk + 4);
      float4 a1  = *reinterpret_cast<const float4*>(pw1 + kk);
      float4 a1b = *reinterpret_cast<const float4*>(pw1 + kk + 4);
#pragma unroll
      for (int bb = 0; bb < 4; ++bb) {
        float4 x4  = *reinterpret_cast<const float4*>(px + bb * 264 + kk);
        float4 x4b = *reinterpret_cast<const float4*>(px + bb * 264 + kk + 4);
        acc[bb]     += a0.x*x4.x + a0.y*x4.y + a0.z*x4.z + a0.w*x4.w
                     + a0b.x*x4b.x + a0b.y*x4b.y + a0b.z*x4b.z + a0b.w*x4b.w;
        acc[4 + bb] += a1.x*x4.x + a1.y*x4.y + a1.z*x4.z + a1.w*x4.w
                     + a1b.x*x4b.x + a1b.y*x4b.y + a1b.z*x4b.z + a1b.w*x4b.w;
      }
    }
  }
  // k-half reduce (pad 9 -> conflict-free)
  float* red2 = SH + 8448;
  __syncthreads();
  if (kh == 1) {
    int s = tid - 256;
#pragma unroll
    for (int e = 0; e < 8; ++e) red2[s * 9 + e] = acc[e];
  }
  __syncthreads();
  float* SA = SH + 10752;          // [32][66]
  if (kh == 0) {
#pragma unroll
    for (int e = 0; e < 8; ++e) acc[e] += red2[tid * 9 + e];
    float b0 = p.fc_b[jbase + 2 * jl];
    float b1 = p.fc_b[jbase + 2 * jl + 1];
#pragma unroll
    for (int bb = 0; bb < 4; ++bb) {
      int b = (bg << 2) + bb;
      float v0 = acc[bb] + b0, v1 = acc[4 + bb] + b1;
      union { double d; float2 f; } uu; uu.f = make_float2(v0, v1);
      __builtin_nontemporal_store(uu.d, reinterpret_cast<double*>(
          p.out + (size_t)b * TT * VV + (size_t)t * VV + jbase + 2 * jl));
      SA[b * 66 + 2 * jl] = v0; SA[b * 66 + 2 * jl + 1] = v1;
    }
  }
  __syncthreads();
  if (tid < 32) {                   // first-max over this tile's 64 j
    float bv = -FLTMAX; int bi = 0;
    for (int jj = 0; jj < 64; ++jj) {
      float v = SA[tid * 66 + jj];
      if (v > bv) { bv = v; bi = jbase + jj; }
    }
    stc2((float*)&p.cand[fcid * 32 + tid], bv, __int_as_float(bi));
  }
  __syncthreads();
}

// AMred: block b (0..31) reduces 500 candidates -> p.tok[b] (argmax steps only)
__device__ __forceinline__ void amred(const Par& p, float* SH)
{
  const int tid = threadIdx.x;
  const int b = blockIdx.x;
  float bv = -FLTMAX; int bi = 0x7fffffff;
  if (tid < NFC) {
    float2 cv = ldc2((const float*)&p.cand[tid * 32 + b]);
    bv = cv.x; bi = __float_as_int(cv.y);
  }
  float* sv = SH; int* si = (int*)(SH + 512);
  sv[tid] = bv; si[tid] = bi;
  __syncthreads();
  for (int s = 256; s > 0; s >>= 1) {
    if (tid < s) {
      float ov = sv[tid + s]; int oi = si[tid + s];
      if (ov > sv[tid] || (ov == sv[tid] && oi < si[tid])) { sv[tid] = ov; si[tid] = oi; }
    }
    __syncthreads();
  }
  if (tid == 0)
    __hip_atomic_store(p.tok + b, si[0], __ATOMIC_RELAXED, __HIP_MEMORY_SCOPE_AGENT);
}

// ---------------------------------------------------------------------------
__global__ __launch_bounds__(BLK, 4) void mega(Par p) {
  __shared__ __attribute__((aligned(16))) float SH[12928];
  __shared__ int stok[32];

  const int tid = threadIdx.x;
  const int bid = blockIdx.x;
  const int gid = bid * BLK + tid;
  int gen = 0;

  // ---- init
  for (int i = gid * 2; i < 2 * BB * HH; i += GRID * BLK * 2)
    stc2(p.hA0 + i, 0.f, 0.f);                       // hA0,hA1 contiguous
  for (int i = gid * 2; i < 2 * BB * HH; i += GRID * BLK * 2)
    stc2(p.hBall + 62 * BB * HH + i, 0.f, 0.f);      // hB slots 62,63 (enc ping-pong)
  if (tid < 128) {
    if (bid < 256) p.cA[bid * 128 + tid] = 0.f;
    else           p.cB[(bid - 256) * 128 + tid] = 0.f;
  }
  for (long g2 = gid; g2 < (long)BB * VV; g2 += (long)GRID * BLK) {
    int b = (int)(g2 / VV), v = (int)(g2 - (long)b * VV);
    __builtin_nontemporal_store(0.f, p.out + (size_t)b * TT * VV + v);
  }
  gbar(p.arr, p.gen, ++gen);

  // ---- encoder: L0(tt) on blocks 0..255 || L1(tt-1) on 256..511
  for (int tt = 0; tt <= SS; ++tt) {
    const int par = tt & 1;
    float* hA_w = par ? p.hA1 : p.hA0;
    float* hA_r = par ? p.hA0 : p.hA1;
    if (bid < 256) {
      if (tt < SS) {
        if (tid < 32) stok[tid] = p.src[tid * SS + tt];
        __syncthreads();
        const int u0 = bid * 4;
        float acc[16] = {0.f};
        lstm_accum(p.enc_embed, stok, nullptr, EE, p.enc_wih0, u0, acc, SH);
        lstm_accum(nullptr, nullptr, hA_r, HH, p.enc_whh0, u0, acc, SH);
        lstm_finish(p.enc_b0, u0, acc, p.cA + bid * 128, hA_w, SH);
      }
    } else {
      if (tt >= 1) {
        const int te = tt - 1;
        float* hB_w = p.hBall + (size_t)((te & 1) ? 63 : 62) * BB * HH;
        float* hB_r = p.hBall + (size_t)((te & 1) ? 62 : 63) * BB * HH;
        const int u0 = (bid - 256) * 4;
        float acc[16] = {0.f};
        lstm_accum(nullptr, nullptr, hA_r, HH, p.enc_wih1, u0, acc, SH);
        lstm_accum(nullptr, nullptr, hB_r, HH, p.enc_whh1, u0, acc, SH);
        lstm_finish(p.enc_b1, u0, acc, p.cB + (bid - 256) * 128, hB_w, SH);
      }
    }
    gbar(p.arr, p.gen, ++gen);
  }

  // ---- decoder with deferred teacher-step FC (batched flushes of 4)
  int pend[4]; int npend = 0;
  for (int k = 0; k < TT - 1; ++k) {
    const int par = k & 1;
    float* hA_r = par ? p.hA0 : p.hA1;    // k=0 -> hA1 (enc final)
    float* hA_w = par ? p.hA1 : p.hA0;
    float* hB_r = p.hBall + (size_t)((k + 63) & 63) * BB * HH;  // k=0 -> slot63
    float* hB_w = p.hBall + (size_t)k * BB * HH;
    const bool teach = (k == 0) || (p.tmask[k] > 0);

    if (!teach) {
      // A: inline FC for logits t=k (needed by this step's argmax)
      if (bid < NFC) fc_tile(p, hB_r, k, bid, SH);
      gbar(p.arr, p.gen, ++gen);
      // B: amred -> p.tok
      if (bid < 32) amred(p, SH);
      gbar(p.arr, p.gen, ++gen);
    }
    // L0 || L1h
    {
      float accB[16];
      if (bid < 256) {
        if (tid < 32) stok[tid] = teach ? p.tgt[tid * TT + k] : ldci(p.tok + tid);
        __syncthreads();
        const int u0 = bid * 4;
        float acc[16] = {0.f};
        lstm_accum(p.dec_embed, stok, nullptr, EE, p.dec_wih0, u0, acc, SH);
        lstm_accum(nullptr, nullptr, hA_r, HH, p.dec_whh0, u0, acc, SH);
        lstm_finish(p.dec_b0, u0, acc, p.cA + bid * 128, hA_w, SH);
      } else {
#pragma unroll
        for (int q = 0; q < 16; ++q) accB[q] = 0.f;
        lstm_accum(nullptr, nullptr, hB_r, HH, p.dec_whh1, (bid - 256) * 4, accB, SH);
      }
      gbar(p.arr, p.gen, ++gen);
      // L1x + cell
      if (bid >= 256) {
        const int u0 = (bid - 256) * 4;
        lstm_accum(nullptr, nullptr, hA_w, HH, p.dec_wih1, u0, accB, SH);
        lstm_finish(p.dec_b1, u0, accB, p.cB + (bid - 256) * 128, hB_w, SH);
      }
      gbar(p.arr, p.gen, ++gen);
    }
    // queue decision for logits t=k+1 (from hB(k), just written):
    // step k+1 argmax -> it inlines; else (teacher step or t=63) -> defer.
    {
      const int nt_ = k + 1;
      const bool nt_inline = (nt_ <= TT - 2) && (p.tmask[nt_] <= 0);
      if (!nt_inline) { pend[npend] = nt_; ++npend; }
      if (npend == 4) {
        if (bid < NFC) {
#pragma unroll
          for (int i = 0; i < 4; ++i) {
            const int tq = pend[i];
            fc_tile(p, p.hBall + (size_t)(tq - 1) * BB * HH, tq, bid, SH);
          }
        }
        npend = 0;
        gbar(p.arr, p.gen, ++gen);
      }
    }
  }
  // ---- final flush of remaining deferred logits (includes t=63)
  if (bid < NFC) {
    for (int i = 0; i < npend; ++i) {
      const int tq = pend[i];
      fc_tile(p, p.hBall + (size_t)(tq - 1) * BB * HH, tq, bid, SH);
    }
  }
}

// ---------------------------------------------------------------------------
extern "C" void kernel_launch(void* const* d_in, const int* in_sizes, int n_in,
                              void* d_out, int out_size, void* d_ws, size_t ws_size,
                              hipStream_t stream) {
  Par p;
  p.src       = (const int*)d_in[0];
  p.tgt       = (const int*)d_in[1];
  p.tmask     = (const int*)d_in[2];
  p.enc_embed = (const float*)d_in[3];
  p.dec_embed = (const float*)d_in[4];
  p.enc_wih0  = (const float*)d_in[5];
  p.enc_whh0  = (const float*)d_in[6];
  p.enc_b0    = (const float*)d_in[7];
  p.enc_wih1  = (const float*)d_in[8];
  p.enc_whh1  = (const float*)d_in[9];
  p.enc_b1    = (const float*)d_in[10];
  p.dec_wih0  = (const float*)d_in[11];
  p.dec_whh0  = (const float*)d_in[12];
  p.dec_b0    = (const float*)d_in[13];
  p.dec_wih1  = (const float*)d_in[14];
  p.dec_whh1  = (const float*)d_in[15];
  p.dec_b1    = (const float*)d_in[16];
  p.fc_w      = (const float*)d_in[17];
  p.fc_b      = (const float*)d_in[18];
  p.out       = (float*)d_out;

  p.arr = (int*)d_ws;                            // 512 slots x 64B
  p.gen = (int*)((char*)d_ws + 32768);           // 8 slots x 64B
  p.tok = (int*)((char*)d_ws + 33536);           // 32 ints
  float* f = (float*)((char*)d_ws + 36864);
  p.hA0   = f; f += BB * HH;
  p.hA1   = f; f += BB * HH;
  p.hBall = f; f += (size_t)64 * BB * HH;        // 2,097,152 floats (8MB)
  p.cA    = f; f += 256 * 128;
  p.cB    = f; f += 256 * 128;
  p.cand  = (float2*)f; f += NFC * 32 * 2;

  hipMemsetAsync(d_ws, 0, 36864, stream);
  mega<<<dim3(GRID), dim3(BLK), 0, stream>>>(p);
}